// Round 1
// baseline (691.789 us; speedup 1.0000x reference)
//
#include <hip/hip_runtime.h>
#include <math.h>

// Problem constants (from reference): B=512, NQ=1, G=1000, H=8, IN=256, E=128, KD=16
#define GG   1000
#define HH   8
#define KDIM 16
#define EDIM 128
#define INDIM 256
#define BDIM 256

__global__ __launch_bounds__(BDIM) void decoder_kernel(
    const float* __restrict__ dIn,    // (B,1,256)
    const float* __restrict__ K,      // (8,B,1000,16)
    const float* __restrict__ V,      // (8,B,1000,16)
    const float* __restrict__ Vout,   // (B,1000,128)
    const int*   __restrict__ mask,   // (B,1,1000)
    const float* __restrict__ Wemb,   // (128,256)
    const float* __restrict__ bemb,   // (128,)
    const float* __restrict__ Wq,     // (8,128,16)
    const float* __restrict__ Wout,   // (8,16,128)
    const float* __restrict__ WQ2,    // (128,128)  (= W_q[0])
    float* __restrict__ out,          // (B,1000)
    int B)
{
    const int b = blockIdx.x;
    const int t = threadIdx.x;

    __shared__ __align__(16) float s_din[INDIM];
    __shared__ __align__(16) float s_emb[EDIM];
    __shared__ __align__(16) float s_q[HH][KDIM];
    __shared__ int   s_mask[GG];
    __shared__ float s_attn[HH][GG];
    __shared__ __align__(16) float s_hp[HH][8][KDIM];
    __shared__ float s_invsum[HH];
    __shared__ float s_heads[HH * KDIM];
    __shared__ float s_ctx[EDIM];
    __shared__ __align__(16) float s_q2[EDIM];

    // ---- Phase 0: stage decoder_input row + mask ----
    s_din[t] = dIn[(size_t)b * INDIM + t];
    for (int g = t; g < GG; g += BDIM) s_mask[g] = mask[(size_t)b * GG + g];
    __syncthreads();

    // ---- Phase 1: emb = din @ Wemb^T + bemb  (E=128 outputs) ----
    if (t < EDIM) {
        float acc = bemb[t];
        const float* w = Wemb + (size_t)t * INDIM;
        #pragma unroll 4
        for (int i = 0; i < INDIM; i += 4) {
            float4 wv = *(const float4*)(w + i);
            acc += wv.x * s_din[i] + wv.y * s_din[i + 1] +
                   wv.z * s_din[i + 2] + wv.w * s_din[i + 3];
        }
        s_emb[t] = acc;
    }
    __syncthreads();

    // ---- Phase 2: Q[h][k] = sum_e emb[e]*Wq[h,e,k], folded 1/sqrt(16) ----
    if (t < HH * KDIM) {
        int h = t >> 4, k = t & 15;
        float acc = 0.f;
        const float* w = Wq + (size_t)h * EDIM * KDIM + k;
        #pragma unroll 8
        for (int e = 0; e < EDIM; ++e) acc += s_emb[e] * w[e * KDIM];
        s_q[h][k] = acc * 0.25f;  // 1/sqrt(KD)
    }
    __syncthreads();

    // ---- Phase 3: compat[h][g] = Q[h] . K[h,b,g,:]  (masked -> -1e30) ----
    for (int h = 0; h < HH; ++h) {
        const float* Kh = K + ((size_t)h * B + b) * (size_t)(GG * KDIM);
        float4 q0 = *(const float4*)&s_q[h][0];
        float4 q1 = *(const float4*)&s_q[h][4];
        float4 q2 = *(const float4*)&s_q[h][8];
        float4 q3 = *(const float4*)&s_q[h][12];
        for (int g = t; g < GG; g += BDIM) {
            float c = -1e30f;
            if (s_mask[g] != 0) {
                const float4* kp = (const float4*)(Kh + (size_t)g * KDIM);
                float4 k0 = kp[0], k1 = kp[1], k2 = kp[2], k3 = kp[3];
                c  = q0.x * k0.x + q0.y * k0.y + q0.z * k0.z + q0.w * k0.w;
                c += q1.x * k1.x + q1.y * k1.y + q1.z * k1.z + q1.w * k1.w;
                c += q2.x * k2.x + q2.y * k2.y + q2.z * k2.z + q2.w * k2.w;
                c += q3.x * k3.x + q3.y * k3.y + q3.z * k3.z + q3.w * k3.w;
            }
            s_attn[h][g] = c;
        }
    }
    __syncthreads();

    // ---- Phase 4: per-head softmax (32 lanes per head), 1/sum deferred ----
    {
        int h = t >> 5;      // 0..7
        int lane = t & 31;
        float m = -1e30f;
        for (int g = lane; g < GG; g += 32) m = fmaxf(m, s_attn[h][g]);
        #pragma unroll
        for (int off = 16; off; off >>= 1) m = fmaxf(m, __shfl_xor(m, off, 32));
        float s = 0.f;
        for (int g = lane; g < GG; g += 32) {
            float e = __expf(s_attn[h][g] - m);   // masked rows underflow to exactly 0
            s_attn[h][g] = e;
            s += e;
        }
        #pragma unroll
        for (int off = 16; off; off >>= 1) s += __shfl_xor(s, off, 32);
        if (lane == 0) s_invsum[h] = 1.f / s;
    }
    __syncthreads();

    // ---- Phase 5: heads[h][k] = invsum[h] * sum_g attn[h][g]*V[h,b,g,k] ----
    {
        int h   = t >> 5;         // 0..7  (2 heads per wave)
        int sub = (t >> 2) & 7;   // 0..7  g-subgroup
        int k4  = t & 3;          // float4 slot within the 16-wide row
        const float* Vh = V + ((size_t)h * B + b) * (size_t)(GG * KDIM);
        float4 acc = make_float4(0.f, 0.f, 0.f, 0.f);
        for (int g = sub; g < GG; g += 8) {
            float a = s_attn[h][g];
            if (a != 0.f) {
                float4 v = *(const float4*)(Vh + (size_t)g * KDIM + k4 * 4);
                acc.x += a * v.x; acc.y += a * v.y;
                acc.z += a * v.z; acc.w += a * v.w;
            }
        }
        s_hp[h][sub][k4 * 4 + 0] = acc.x;
        s_hp[h][sub][k4 * 4 + 1] = acc.y;
        s_hp[h][sub][k4 * 4 + 2] = acc.z;
        s_hp[h][sub][k4 * 4 + 3] = acc.w;
    }
    __syncthreads();
    if (t < HH * KDIM) {
        int h = t >> 4, k = t & 15;
        float sum = 0.f;
        #pragma unroll
        for (int sub = 0; sub < 8; ++sub) sum += s_hp[h][sub][k];
        s_heads[t] = sum * s_invsum[h];
    }
    __syncthreads();

    // ---- Phase 6: context[e] = sum_{h,k} heads[h,k]*Wout[h,k,e] ----
    if (t < EDIM) {
        float acc = 0.f;
        #pragma unroll 8
        for (int j = 0; j < HH * KDIM; ++j) acc += s_heads[j] * Wout[(size_t)j * EDIM + t];
        s_ctx[t] = acc;
    }
    __syncthreads();
    // ---- Phase 7: Q2[f] = (1/sqrt(128)) * sum_e ctx[e]*WQ2[e,f] ----
    if (t < EDIM) {
        float acc = 0.f;
        #pragma unroll 8
        for (int e = 0; e < EDIM; ++e) acc += s_ctx[e] * WQ2[(size_t)e * EDIM + t];
        s_q2[t] = acc * 0.08838834764831845f;  // 1/sqrt(E)
    }
    __syncthreads();

    // ---- Phase 8: out[b,g] = 10*tanh( Q2 . Vout[b,g,:] ) ----
    const float* Vo = Vout + (size_t)b * (size_t)(GG * EDIM);
    for (int g = t; g < GG; g += BDIM) {
        const float4* vp = (const float4*)(Vo + (size_t)g * EDIM);
        float acc = 0.f;
        #pragma unroll 8
        for (int j = 0; j < EDIM / 4; ++j) {
            float4 v = vp[j];
            float4 q = *(const float4*)&s_q2[j * 4];
            acc += v.x * q.x + v.y * q.y + v.z * q.z + v.w * q.w;
        }
        out[(size_t)b * GG + g] = 10.f * tanhf(acc);
    }
}

extern "C" void kernel_launch(void* const* d_in, const int* in_sizes, int n_in,
                              void* d_out, int out_size, void* d_ws, size_t ws_size,
                              hipStream_t stream) {
    const float* dIn  = (const float*)d_in[0];
    const float* K    = (const float*)d_in[1];
    const float* V    = (const float*)d_in[2];
    const float* Vout = (const float*)d_in[3];
    const int*   mask = (const int*)d_in[4];
    const float* Wemb = (const float*)d_in[5];
    const float* bemb = (const float*)d_in[6];
    const float* Wq   = (const float*)d_in[7];
    const float* Wout = (const float*)d_in[8];
    const float* WQ2  = (const float*)d_in[9];
    float* out = (float*)d_out;

    int B = in_sizes[0] / INDIM;   // decoder_input is (B,1,256)
    decoder_kernel<<<dim3(B), dim3(BDIM), 0, stream>>>(
        dIn, K, V, Vout, mask, Wemb, bemb, Wq, Wout, WQ2, out, B);
}

// Round 2
// 677.077 us; speedup vs baseline: 1.0217x; 1.0217x over previous
//
#include <hip/hip_runtime.h>
#include <math.h>

// Problem constants: B=512, NQ=1, G=1000, H=8, IN=256, E=128, KD=16
#define GG    1000
#define HH    8
#define KDIM  16
#define EDIM  128
#define INDIM 256

// ---------------- K1: per-b  emb = din@Wemb^T + b ; Q = emb@Wq * 1/sqrt(KD) ----
__global__ __launch_bounds__(128) void k1_embq(
    const float* __restrict__ dIn,   // (B,256)
    const float* __restrict__ Wemb,  // (128,256)
    const float* __restrict__ bemb,  // (128)
    const float* __restrict__ Wq,    // (8,128,16)
    float* __restrict__ qout,        // ws: (B,128) = (B,H,KD)
    int B)
{
    const int b = blockIdx.x, t = threadIdx.x;
    __shared__ __align__(16) float s_din[INDIM];
    __shared__ float s_emb[EDIM];

    s_din[t]       = dIn[(size_t)b * INDIM + t];
    s_din[t + 128] = dIn[(size_t)b * INDIM + t + 128];
    __syncthreads();

    float acc = bemb[t];
    const float* w = Wemb + (size_t)t * INDIM;
    #pragma unroll 4
    for (int i = 0; i < INDIM; i += 4) {
        float4 wv = *(const float4*)(w + i);
        acc += wv.x * s_din[i] + wv.y * s_din[i + 1] +
               wv.z * s_din[i + 2] + wv.w * s_din[i + 3];
    }
    s_emb[t] = acc;
    __syncthreads();

    const int h = t >> 4, k = t & 15;
    float q = 0.f;
    const float* wq = Wq + (size_t)h * EDIM * KDIM + k;
    #pragma unroll 8
    for (int e = 0; e < EDIM; ++e) q += s_emb[e] * wq[e * KDIM];
    qout[(size_t)b * EDIM + t] = q * 0.25f;   // fold 1/sqrt(16)
}

// ---------------- K2: per-(h,b) attention -> heads[b, h*16+k] ----------------
__global__ __launch_bounds__(256) void k2_attn(
    const float* __restrict__ K,     // (8,B,1000,16)
    const float* __restrict__ V,     // (8,B,1000,16)
    const int*   __restrict__ mask,  // (B,1000)
    const float* __restrict__ qin,   // ws: (B,128)
    float* __restrict__ headsout,    // ws: (B,128)
    int B)
{
    const int bx = blockIdx.x;
    const int b = bx % B, h = bx / B;
    const int t = threadIdx.x;

    __shared__ int   s_mask[GG];
    __shared__ float s_attn[GG];
    __shared__ __align__(16) float s_q[KDIM];
    __shared__ float s_red[8];
    __shared__ __align__(16) float s_hp[64][KDIM];
    __shared__ float s_bmax, s_binv;

    if (t < KDIM) s_q[t] = qin[(size_t)b * EDIM + h * KDIM + t];
    for (int g = t; g < GG; g += 256) s_mask[g] = mask[(size_t)b * GG + g];
    __syncthreads();

    // compat + running max
    const float* Kh = K + ((size_t)h * B + b) * (size_t)(GG * KDIM);
    float4 q0 = *(const float4*)&s_q[0];
    float4 q1 = *(const float4*)&s_q[4];
    float4 q2 = *(const float4*)&s_q[8];
    float4 q3 = *(const float4*)&s_q[12];
    float lmax = -1e30f;
    for (int g = t; g < GG; g += 256) {
        float c = -1e30f;
        if (s_mask[g] != 0) {
            const float4* kp = (const float4*)(Kh + (size_t)g * KDIM);
            float4 k0 = kp[0], k1 = kp[1], k2 = kp[2], k3 = kp[3];
            c  = q0.x * k0.x + q0.y * k0.y + q0.z * k0.z + q0.w * k0.w;
            c += q1.x * k1.x + q1.y * k1.y + q1.z * k1.z + q1.w * k1.w;
            c += q2.x * k2.x + q2.y * k2.y + q2.z * k2.z + q2.w * k2.w;
            c += q3.x * k3.x + q3.y * k3.y + q3.z * k3.z + q3.w * k3.w;
        }
        s_attn[g] = c;
        lmax = fmaxf(lmax, c);
    }
    // block max (64-wide shuffle, then 4 waves via LDS)
    #pragma unroll
    for (int off = 32; off; off >>= 1) lmax = fmaxf(lmax, __shfl_xor(lmax, off));
    const int wid = t >> 6;
    if ((t & 63) == 0) s_red[wid] = lmax;
    __syncthreads();
    if (t == 0) s_bmax = fmaxf(fmaxf(s_red[0], s_red[1]), fmaxf(s_red[2], s_red[3]));
    __syncthreads();
    const float m = s_bmax;

    // exp + block sum
    float lsum = 0.f;
    for (int g = t; g < GG; g += 256) {
        float e = __expf(s_attn[g] - m);   // masked rows underflow to exactly 0
        s_attn[g] = e;
        lsum += e;
    }
    #pragma unroll
    for (int off = 32; off; off >>= 1) lsum += __shfl_xor(lsum, off);
    if ((t & 63) == 0) s_red[4 + wid] = lsum;
    __syncthreads();
    if (t == 0) s_binv = 1.f / (s_red[4] + s_red[5] + s_red[6] + s_red[7]);
    __syncthreads();

    // attn . V   (64 g-subgroups x 4 float4-slots; wave covers 1KB contiguous)
    const int sub = t >> 2, k4 = t & 3;
    const float* Vh = V + ((size_t)h * B + b) * (size_t)(GG * KDIM);
    float4 acc = make_float4(0.f, 0.f, 0.f, 0.f);
    for (int g = sub; g < GG; g += 64) {
        float a = s_attn[g];
        if (a != 0.f) {
            float4 v = *(const float4*)(Vh + (size_t)g * KDIM + k4 * 4);
            acc.x += a * v.x; acc.y += a * v.y;
            acc.z += a * v.z; acc.w += a * v.w;
        }
    }
    s_hp[sub][k4 * 4 + 0] = acc.x;
    s_hp[sub][k4 * 4 + 1] = acc.y;
    s_hp[sub][k4 * 4 + 2] = acc.z;
    s_hp[sub][k4 * 4 + 3] = acc.w;
    __syncthreads();
    if (t < KDIM) {
        float s = 0.f;
        #pragma unroll
        for (int i = 0; i < 64; ++i) s += s_hp[i][t];
        headsout[(size_t)b * EDIM + h * KDIM + t] = s * s_binv;
    }
}

// ------------- K3: per-(b, quarter) ctx/Q2 GEMVs + z-output over Vout --------
__global__ __launch_bounds__(256) void k3_out(
    const float* __restrict__ Vout,    // (B,1000,128)
    const float* __restrict__ headsin, // ws: (B,128)
    const float* __restrict__ Wout,    // (8,16,128) = (128,128)
    const float* __restrict__ WQ2,     // (128,128)
    float* __restrict__ out,           // (B,1000)
    int B)
{
    const int bx = blockIdx.x;
    const int b = bx >> 2, chunk = bx & 3;
    const int t = threadIdx.x;
    __shared__ float s_heads[EDIM];
    __shared__ float s_ctx[EDIM];
    __shared__ __align__(16) float s_q2[EDIM];

    if (t < EDIM) s_heads[t] = headsin[(size_t)b * EDIM + t];
    __syncthreads();
    if (t < EDIM) {
        float acc = 0.f;
        #pragma unroll 8
        for (int j = 0; j < EDIM; ++j) acc += s_heads[j] * Wout[(size_t)j * EDIM + t];
        s_ctx[t] = acc;
    }
    __syncthreads();
    if (t < EDIM) {
        float acc = 0.f;
        #pragma unroll 8
        for (int e = 0; e < EDIM; ++e) acc += s_ctx[e] * WQ2[(size_t)e * EDIM + t];
        s_q2[t] = acc * 0.08838834764831845f;  // fold 1/sqrt(128)
    }
    __syncthreads();

    // 32 lanes per row: 512B fully-coalesced per row, 2 rows per wave
    const int lane = t & 31;
    const int rowoff = t >> 5;  // 0..7
    float4 q = *(const float4*)&s_q2[lane * 4];
    const float* Vo = Vout + (size_t)b * (size_t)(GG * EDIM);
    const int g0 = chunk * (GG / 4);
    const int g1 = g0 + (GG / 4);
    for (int g = g0 + rowoff; g < g1; g += 8) {
        const float4* vp = (const float4*)(Vo + (size_t)g * EDIM);
        float4 v = vp[lane];
        float acc = v.x * q.x + v.y * q.y + v.z * q.z + v.w * q.w;
        #pragma unroll
        for (int off = 16; off; off >>= 1) acc += __shfl_xor(acc, off, 32);
        if (lane == 0) out[(size_t)b * GG + g] = 10.f * tanhf(acc);
    }
}

extern "C" void kernel_launch(void* const* d_in, const int* in_sizes, int n_in,
                              void* d_out, int out_size, void* d_ws, size_t ws_size,
                              hipStream_t stream) {
    const float* dIn  = (const float*)d_in[0];
    const float* K    = (const float*)d_in[1];
    const float* V    = (const float*)d_in[2];
    const float* Vout = (const float*)d_in[3];
    const int*   mask = (const int*)d_in[4];
    const float* Wemb = (const float*)d_in[5];
    const float* bemb = (const float*)d_in[6];
    const float* Wq   = (const float*)d_in[7];
    const float* Wout = (const float*)d_in[8];
    const float* WQ2  = (const float*)d_in[9];
    float* out = (float*)d_out;

    const int B = in_sizes[0] / INDIM;
    float* ws_q     = (float*)d_ws;            // B*128 floats
    float* ws_heads = ws_q + (size_t)B * EDIM; // B*128 floats

    k1_embq<<<dim3(B), dim3(128), 0, stream>>>(dIn, Wemb, bemb, Wq, ws_q, B);
    k2_attn<<<dim3(HH * B), dim3(256), 0, stream>>>(K, V, mask, ws_q, ws_heads, B);
    k3_out<<<dim3(B * 4), dim3(256), 0, stream>>>(Vout, ws_heads, Wout, WQ2, out, B);
}